// Round 6
// baseline (130.251 us; speedup 1.0000x reference)
//
#include <hip/hip_runtime.h>
#include <cstdint>
#include <cstddef>

// Problem constants
#define B_DIM 4096   // batch (GEMM M)
#define S_DIM 2048   // states (GEMM N)
#define D_DIM 2496   // feature dim (GEMM K)
#define QSCALE 127.0f
#define QSCALE2 16129.0f   // 127^2
#define KC 39        // k-chunks of 64 bytes

typedef __attribute__((ext_vector_type(4))) int int4v;

// R12: first round with real gemm counters: 43.2us, MfmaUtil 17%, VALUBusy
// 14%, Occupancy 18%, 2.56M LDS bank-conflict cycles -> latency-bound with
// ~70% stall, not any of the R7-R10 theories' regimes. R8/R9's neutrality is
// reinterpreted: their gemm gain was cancelled by scattered prep writes.
// Fix both halves this time:
//  - prep: block-per-rowblock TRANSPOSE prep. Reads stay row-contiguous
//    float4; writes become perfectly contiguous 1KB/chunk (offset 4t).
//    Slot-major chunk algebra (harness-verified in R8): chunk = 16 rows x
//    64 k-bytes stored [slot4][row16][16B]; byte offset of (slot,row,f4*4)
//    = 4*threadIdx; fragment read for mfma_i32_16x16x64_i8 = lane*16.
//  - gemm: NO LDS, NO barriers. Each 64x64 output tile = one independent
//    64-thread block; fragments load direct global->VGPR (coalesced 1KB per
//    load) through L1/L2 (B panel 0.64MB/XCD L2-resident via R9 mapping);
//    depth-2 register pipeline with two named sets (rule #20). Latency is
//    hidden by 8 independent waves/CU instead of barrier-locked drains.
struct __attribute__((aligned(8))) uc8 { unsigned char c[8]; };

// ---------------------------------------------------------------------------
// Prep: grid = 768 blocks = (256 A-rowblocks + 128 B-rowblocks) x 2 k-halves.
// Block handles 16 rows x chunks [c0,c1). Thread t: slot=t>>6, row=(t>>2)&15,
// f4=t&3. Read float4 at src[row][c*64 + slot*16 + f4*4] (row-contiguous),
// write u32 at chunkbase + 4t (block-contiguous 1KB). Partial squared norms
// per row go to xsqp/msqp[half][row]; gemm epilogue sums the two halves.
__global__ __launch_bounds__(256) void prep_kernel(
    const float* __restrict__ X, const float* __restrict__ Mx,
    unsigned char* __restrict__ Xq, unsigned char* __restrict__ Mq,
    float* __restrict__ xsqp, float* __restrict__ msqp)
{
    const int t    = threadIdx.x;
    const int bid  = blockIdx.x;
    const int rb   = bid >> 1;        // 0..383
    const int half = bid & 1;
    const int c0   = half ? 20 : 0;
    const int c1   = half ? KC : 20;

    const float* src; unsigned char* dst; float* part;
    if (rb < 256) {
        src  = X  + (size_t)(rb * 16) * D_DIM;
        dst  = Xq + (size_t)rb * (KC * 1024);
        part = xsqp + half * B_DIM + rb * 16;
    } else {
        const int r = rb - 256;
        src  = Mx + (size_t)(r * 16) * D_DIM;
        dst  = Mq + (size_t)r * (KC * 1024);
        part = msqp + half * S_DIM + r * 16;
    }

    const int slot = t >> 6;
    const int r16  = (t >> 2) & 15;
    const int f4   = t & 3;
    const float* srow = src + (size_t)r16 * D_DIM + slot * 16 + f4 * 4;

    float acc = 0.f;
    #pragma unroll 4
    for (int c = c0; c < c1; ++c) {
        const float4 v = *(const float4*)(srow + c * 64);
        acc += v.x * v.x + v.y * v.y + v.z * v.z + v.w * v.w;
        const unsigned int q0 = (unsigned char)__float2int_rn(v.x * QSCALE);
        const unsigned int q1 = (unsigned char)__float2int_rn(v.y * QSCALE);
        const unsigned int q2 = (unsigned char)__float2int_rn(v.z * QSCALE);
        const unsigned int q3 = (unsigned char)__float2int_rn(v.w * QSCALE);
        *(unsigned int*)(dst + (size_t)c * 1024 + t * 4) =
            q0 | (q1 << 8) | (q2 << 16) | (q3 << 24);
    }

    __shared__ float red[256];
    red[t] = acc;
    __syncthreads();
    if (t < 16) {
        float s = 0.f;
        #pragma unroll
        for (int s4 = 0; s4 < 4; ++s4)
            #pragma unroll
            for (int f = 0; f < 4; ++f)
                s += red[s4 * 64 + t * 4 + f];
        part[t] = s;
    }
}

// ---------------------------------------------------------------------------
// GEMM: one 64-thread block per 64x64 output tile; 2048 blocks. No LDS, no
// barriers. Fragments: af[i]/bf[j] = 1KB coalesced load at
// (rowblock*39 + t)*1024 + lane*16. Depth-2 pipeline: two named sets.
__global__ __launch_bounds__(64, 2) void gemm_kernel(
    const unsigned char* __restrict__ A,   // slot-major [256 rb][39 kc][1024]
    const unsigned char* __restrict__ Bt,  // slot-major [128 rb][39 kc][1024]
    const float* __restrict__ xsqp, const float* __restrict__ msqp,
    float* __restrict__ C)
{
    constexpr int N = S_DIM;
    const int lane = threadIdx.x;

    // XCD mapping (m09: xcd = bid&7 round-robin): per XCD 4 col-tiles
    // (B panel 4*64*2496 = 0.64MB, L2-resident); A row-tile shared by the
    // 4 adjacently-launched blocks of an l&3 group.
    const int bid  = blockIdx.x;
    const int xcd  = bid & 7;
    const int l    = bid >> 3;            // 0..255 within XCD
    const int bn_t = xcd * 4 + (l & 3);   // 0..31
    const int bm_t = l >> 2;              // 0..63

    // Fragment base pointers (lane*16 inside each 1KB chunk).
    const unsigned char* pA[4];
    const unsigned char* pB[4];
    #pragma unroll
    for (int i = 0; i < 4; ++i) {
        pA[i] = A  + (size_t)((bm_t * 4 + i) * KC) * 1024 + lane * 16;
        pB[i] = Bt + (size_t)((bn_t * 4 + i) * KC) * 1024 + lane * 16;
    }

    int4v acc[4][4] = {};
    int4v af0[4], bf0[4], af1[4], bf1[4];

#define LOADT(AF, BF, T) do { \
    const size_t o_ = (size_t)(T) * 1024; \
    _Pragma("unroll") \
    for (int i = 0; i < 4; ++i) { \
        AF[i] = *(const int4v*)(pA[i] + o_); \
        BF[i] = *(const int4v*)(pB[i] + o_); \
    } \
} while (0)

#define COMP(AF, BF) do { \
    _Pragma("unroll") \
    for (int mi = 0; mi < 4; ++mi) \
        _Pragma("unroll") \
        for (int ni = 0; ni < 4; ++ni) \
            acc[mi][ni] = __builtin_amdgcn_mfma_i32_16x16x64_i8( \
                AF[mi], BF[ni], acc[mi][ni], 0, 0, 0); \
} while (0)

    // Prologue: k-steps 0 and 1 in flight.
    LOADT(af0, bf0, 0);
    LOADT(af1, bf1, 1);

    // Main: computes 0..35, loads 2..37 (depth-2, sets strictly alternate).
    for (int t = 0; t < 36; t += 2) {
        COMP(af0, bf0); LOADT(af0, bf0, t + 2);
        COMP(af1, bf1); LOADT(af1, bf1, t + 3);
    }
    // Tail: compute 36 (load 38), 37, 38.
    COMP(af0, bf0); LOADT(af0, bf0, 38);
    COMP(af1, bf1);
    COMP(af0, bf0);

#undef COMP
#undef LOADT

    // Epilogue (verified mapping): col = lane&15, row = (lane>>4)*4 + reg.
    // Norms are two-part sums (prep halves). C = (2*cross/127^2 - xs - ms)/500.
    const int fr   = lane & 15;
    const int row0 = bm_t * 64 + (lane >> 4) * 4;
    const int col0 = bn_t * 64 + fr;
    float ms[4];
    #pragma unroll
    for (int ni = 0; ni < 4; ++ni)
        ms[ni] = msqp[col0 + ni * 16] + msqp[S_DIM + col0 + ni * 16];
    #pragma unroll
    for (int mi = 0; mi < 4; ++mi) {
        #pragma unroll
        for (int r = 0; r < 4; ++r) {
            const int row = row0 + mi * 16 + r;
            const float xs = xsqp[row] + xsqp[B_DIM + row];
            #pragma unroll
            for (int ni = 0; ni < 4; ++ni) {
                const float cr2 = (float)acc[mi][ni][r] * (2.0f / QSCALE2);
                const float v = (cr2 - xs - ms[ni]) * (1.0f / 500.0f);
                C[(size_t)row * N + col0 + ni * 16] = v;
            }
        }
    }
}

// ---------------------------------------------------------------------------
extern "C" void kernel_launch(void* const* d_in, const int* in_sizes, int n_in,
                              void* d_out, int out_size, void* d_ws, size_t ws_size,
                              hipStream_t stream) {
    const float* X  = (const float*)d_in[0];  // [4096, 2496]
    const float* Mx = (const float*)d_in[1];  // [2048, 2496]
    float* out = (float*)d_out;               // [4096, 2048]

    // Workspace (~15.4 MB): Xq slot-major | Mq slot-major | xsqp[2][4096] |
    // msqp[2][2048]
    unsigned char* Xq = (unsigned char*)d_ws;
    unsigned char* Mq = Xq + (size_t)256 * KC * 1024;
    float* xsqp = (float*)(Mq + (size_t)128 * KC * 1024);
    float* msqp = xsqp + 2 * B_DIM;

    prep_kernel<<<768, 256, 0, stream>>>(X, Mx, Xq, Mq, xsqp, msqp);

    // 2048 one-wave blocks: 64 row-tiles x 32 col-tiles, XCD-mapped.
    gemm_kernel<<<2048, 64, 0, stream>>>(Xq, Mq, xsqp, msqp, out);
}

// Round 7
// 123.140 us; speedup vs baseline: 1.0577x; 1.0577x over previous
//
#include <hip/hip_runtime.h>
#include <cstdint>
#include <cstddef>

// Problem constants
#define B_DIM 4096   // batch (GEMM M)
#define S_DIM 2048   // states (GEMM N)
#define D_DIM 2496   // feature dim (GEMM K)
#define QSCALE 127.0f
#define QSCALE2 16129.0f   // 127^2
#define KC 39        // k-chunks of 64 bytes

// R13: compose the two verified-good halves that have never run together.
//  - prep: R12's transpose prep (coalesced 64-B reads AND contiguous 1KB
//    chunk writes, partial norms). R8/R9's prep had scattered 8-B writes
//    that plausibly masked their gemm gain.
//  - gemm: R9's slot-major conflict-free LDS + 3-buffer counted vmcnt(4)
//    pipeline + B-resident XCD mapping (epilogue adapted to 2-part norms).
// This isolates: does zero-bank-conflict + never-draining staging actually
// cut the measured 43.2us latency-bound gemm (MfmaUtil 17%, 2.56M conflict
// cycles)? Null result => declare roofline at baseline.
#define BM 128
#define BN 128
#define BK 64
#define BUFB ((BM + BN) * BK) // 16384 B per buffer (A 8 KB | B 8 KB)

typedef __attribute__((ext_vector_type(4))) int int4v;

// ---------------------------------------------------------------------------
// Prep: grid = 768 blocks = (256 A-rowblocks + 128 B-rowblocks) x 2 k-halves.
// Slot-major chunk (harness-verified): 16 rows x 64 k-bytes stored
// [slot4][row16][16B]; byte offset of (slot,row,f4) = 4*threadIdx; a linear
// 1KB copy (lane*16) IS the i8 16x16x64 fragment (m=lane&15, k16=lane>>4).
// Thread t: slot=t>>6, row=(t>>2)&15, f4=t&3. Reads row-contiguous float4;
// writes u32 at chunkbase + 4t (block-contiguous 1KB). Partial norms to
// xsqp/msqp[half][row]; gemm epilogue sums the halves.
__global__ __launch_bounds__(256) void prep_kernel(
    const float* __restrict__ X, const float* __restrict__ Mx,
    unsigned char* __restrict__ Xq, unsigned char* __restrict__ Mq,
    float* __restrict__ xsqp, float* __restrict__ msqp)
{
    const int t    = threadIdx.x;
    const int bid  = blockIdx.x;
    const int rb   = bid >> 1;        // 0..383
    const int half = bid & 1;
    const int c0   = half ? 20 : 0;
    const int c1   = half ? KC : 20;

    const float* src; unsigned char* dst; float* part;
    if (rb < 256) {
        src  = X  + (size_t)(rb * 16) * D_DIM;
        dst  = Xq + (size_t)rb * (KC * 1024);
        part = xsqp + half * B_DIM + rb * 16;
    } else {
        const int r = rb - 256;
        src  = Mx + (size_t)(r * 16) * D_DIM;
        dst  = Mq + (size_t)r * (KC * 1024);
        part = msqp + half * S_DIM + r * 16;
    }

    const int slot = t >> 6;
    const int r16  = (t >> 2) & 15;
    const int f4   = t & 3;
    const float* srow = src + (size_t)r16 * D_DIM + slot * 16 + f4 * 4;

    float acc = 0.f;
    #pragma unroll 4
    for (int c = c0; c < c1; ++c) {
        const float4 v = *(const float4*)(srow + c * 64);
        acc += v.x * v.x + v.y * v.y + v.z * v.z + v.w * v.w;
        const unsigned int q0 = (unsigned char)__float2int_rn(v.x * QSCALE);
        const unsigned int q1 = (unsigned char)__float2int_rn(v.y * QSCALE);
        const unsigned int q2 = (unsigned char)__float2int_rn(v.z * QSCALE);
        const unsigned int q3 = (unsigned char)__float2int_rn(v.w * QSCALE);
        *(unsigned int*)(dst + (size_t)c * 1024 + t * 4) =
            q0 | (q1 << 8) | (q2 << 16) | (q3 << 24);
    }

    __shared__ float red[256];
    red[t] = acc;
    __syncthreads();
    if (t < 16) {
        float s = 0.f;
        #pragma unroll
        for (int s4 = 0; s4 < 4; ++s4)
            #pragma unroll
            for (int f = 0; f < 4; ++f)
                s += red[s4 * 64 + t * 4 + f];
        part[t] = s;
    }
}

// ---------------------------------------------------------------------------
// global -> LDS direct (async) load, 16 B per lane; contiguous 1KB per issue.
__device__ __forceinline__ void gld_lds16(const unsigned char* g, unsigned char* l) {
    __builtin_amdgcn_global_load_lds(
        (const __attribute__((address_space(1))) unsigned int*)g,
        (__attribute__((address_space(3))) unsigned int*)l,
        16, 0, 0);
}

// ---------------------------------------------------------------------------
__global__ __launch_bounds__(256) void gemm_kernel(
    const unsigned char* __restrict__ A,   // slot-major chunked [256 rb][39 kc][1024]
    const unsigned char* __restrict__ Bt,  // slot-major chunked [128 rb][39 kc][1024]
    const float* __restrict__ xsqp, const float* __restrict__ msqp,
    float* __restrict__ C)
{
    constexpr int N = S_DIM;

    __shared__ __align__(16) unsigned char lds[3 * BUFB];  // 48 KB, 3 buffers

    const int tid  = threadIdx.x;
    const int lane = tid & 63;
    const int wave = tid >> 6;       // 4 waves, 2x2 of 64x64
    const int wm = wave >> 1;
    const int wn = wave & 1;

    // B-panel-resident XCD mapping (R9): xcd = bid&7 round-robin (m09).
    //   bn = 2*xcd + (l&1)  -> B panel 0.64 MB, L2-resident all kernel.
    //   bm = l>>1           -> A-chunk shared by the adjacent l-pair only.
    const int bid = blockIdx.x;
    const int xcd = bid & 7;
    const int l   = bid >> 3;              // 0..63 within XCD
    const int bm  = l >> 1;                // 0..31
    const int bn  = xcd * 2 + (l & 1);     // 0..15

    // Staging: per K-step each wave copies 4 chunks (A rowblocks 2w,2w+1 and
    // B rowblocks 2w,2w+1), each a contiguous 1 KB at base + lane*16.
    const unsigned char* pA0 = A  + (size_t)((bm * 8 + 2 * wave    ) * KC) * 1024 + lane * 16;
    const unsigned char* pA1 = A  + (size_t)((bm * 8 + 2 * wave + 1) * KC) * 1024 + lane * 16;
    const unsigned char* pB0 = Bt + (size_t)((bn * 8 + 2 * wave    ) * KC) * 1024 + lane * 16;
    const unsigned char* pB1 = Bt + (size_t)((bn * 8 + 2 * wave + 1) * KC) * 1024 + lane * 16;
    const int dA0 = (2 * wave) * 1024;            // LDS offsets within buffer
    const int dA1 = dA0 + 1024;
    const int dB0 = 8192 + (2 * wave) * 1024;
    const int dB1 = dB0 + 1024;

    int4v acc[4][4] = {};

    // Fragment read offsets: linear lane*16 within each chunk (conflict-free).
    const int aoff = wm * 4096 + lane * 16;
    const int boff = 8192 + wn * 4096 + lane * 16;

#define STAGE(BUF) do { \
    gld_lds16(pA0, &lds[(BUF) + dA0]); \
    gld_lds16(pA1, &lds[(BUF) + dA1]); \
    gld_lds16(pB0, &lds[(BUF) + dB0]); \
    gld_lds16(pB1, &lds[(BUF) + dB1]); \
    pA0 += 1024; pA1 += 1024; pB0 += 1024; pB1 += 1024; \
} while (0)

#define COMPUTE(BUF) do { \
    int4v af[4], bf[4]; \
    _Pragma("unroll") \
    for (int i = 0; i < 4; ++i) { \
        af[i] = *(const int4v*)&lds[(BUF) + aoff + i * 1024]; \
        bf[i] = *(const int4v*)&lds[(BUF) + boff + i * 1024]; \
    } \
    _Pragma("unroll") \
    for (int mi = 0; mi < 4; ++mi) \
        _Pragma("unroll") \
        for (int ni = 0; ni < 4; ++ni) \
            acc[mi][ni] = __builtin_amdgcn_mfma_i32_16x16x64_i8( \
                af[mi], bf[ni], acc[mi][ni], 0, 0, 0); \
} while (0)

// One step: wait own 4 loads for the tile about to be computed (4 newer stay
// in flight), publish via barrier, then stage tile t+2 into the buffer
// computed at t-1 (safe: all waves passed the barrier after computing it),
// then compute tile t. Never drains vmcnt to 0 in the main loop.
#define STEP(CBUF, SBUF) do { \
    asm volatile("s_waitcnt vmcnt(4)" ::: "memory"); \
    __builtin_amdgcn_s_barrier(); \
    STAGE(SBUF); \
    COMPUTE(CBUF); \
} while (0)

    // Prologue: tiles 0 and 1 in flight (8 loads/wave).
    STAGE(0);
    STAGE(BUFB);

    // Main loop: tiles 0..35 (12 x 3, fully static buffer refs), then 36.
    for (int t = 0; t < 36; t += 3) {
        STEP(0,        2 * BUFB);
        STEP(BUFB,     0       );
        STEP(2 * BUFB, BUFB    );
    }
    STEP(0, 2 * BUFB);   // t=36: stages tile 38 (last), computes tile 36

    // t=37: tile 38's 4 loads still in flight.
    asm volatile("s_waitcnt vmcnt(4)" ::: "memory");
    __builtin_amdgcn_s_barrier();
    COMPUTE(BUFB);
    // t=38: drain.
    asm volatile("s_waitcnt vmcnt(0)" ::: "memory");
    __builtin_amdgcn_s_barrier();
    COMPUTE(2 * BUFB);

#undef STEP
#undef COMPUTE
#undef STAGE

    // Epilogue (verified mapping): col = lane&15, row = (lane>>4)*4 + reg.
    // Norms are two-part sums (prep halves). C = (2*cross/127^2 - xs - ms)/500.
    const int fr   = lane & 15;
    const int row0 = bm * BM + wm * 64 + (lane >> 4) * 4;
    const int col0 = bn * BN + wn * 64 + fr;
    float ms[4];
    #pragma unroll
    for (int ni = 0; ni < 4; ++ni)
        ms[ni] = msqp[col0 + ni * 16] + msqp[S_DIM + col0 + ni * 16];
    #pragma unroll
    for (int mi = 0; mi < 4; ++mi) {
        #pragma unroll
        for (int r = 0; r < 4; ++r) {
            const int row = row0 + mi * 16 + r;
            const float xs = xsqp[row] + xsqp[B_DIM + row];
            #pragma unroll
            for (int ni = 0; ni < 4; ++ni) {
                const float cr2 = (float)acc[mi][ni][r] * (2.0f / QSCALE2);
                const float v = (cr2 - xs - ms[ni]) * (1.0f / 500.0f);
                C[(size_t)row * N + col0 + ni * 16] = v;
            }
        }
    }
}

// ---------------------------------------------------------------------------
extern "C" void kernel_launch(void* const* d_in, const int* in_sizes, int n_in,
                              void* d_out, int out_size, void* d_ws, size_t ws_size,
                              hipStream_t stream) {
    const float* X  = (const float*)d_in[0];  // [4096, 2496]
    const float* Mx = (const float*)d_in[1];  // [2048, 2496]
    float* out = (float*)d_out;               // [4096, 2048]

    // Workspace (~15.4 MB): Xq slot-major | Mq slot-major | xsqp[2][4096] |
    // msqp[2][2048]
    unsigned char* Xq = (unsigned char*)d_ws;
    unsigned char* Mq = Xq + (size_t)256 * KC * 1024;
    float* xsqp = (float*)(Mq + (size_t)128 * KC * 1024);
    float* msqp = xsqp + 2 * B_DIM;

    prep_kernel<<<768, 256, 0, stream>>>(X, Mx, Xq, Mq, xsqp, msqp);

    dim3 grid(512);  // 32 bm x 16 bn via XCD-resident mapping, 2 blocks/CU
    gemm_kernel<<<grid, 256, 0, stream>>>(Xq, Mq, xsqp, msqp, out);
}